// Round 11
// baseline (3367.121 us; speedup 1.0000x reference)
//
#include <hip/hip_runtime.h>
#include <hip/hip_bf16.h>

// MarioDoomPolicyNet: conv stack (4x stride-2 + ELU) -> 2-layer LSTM scan -> heads.
// R11/R12 best-known parts: convall 577us (VGPR 56, occ 46%), total 1706.5.
// R13/R14: split-half conv DEAD (spill / 2x issue). R15: n'=b*64+t layout + scan
//     write-tiling — neutral total (1712.3) but convall WRITE 36.8->4.8MB and layout
//     retained. Non-convall time stuck ~1130us across R8-R15 => each scan ~450-550us
//     (just under convall, invisible in top-5): L2-port-bound streaming 640KB/step on
//     ONE CU per batch elem; 192 CUs idle.
// R16: persistent scan, 4 blocks per b (256 blocks x 256 thr). Per block 256 gate
//     rows: 48 quads in NAMED regs (192 VGPR @ 1 wave/SIMD cap 256) + 16 quads LDS
//     (64KB) = W_hh FULLY resident; zero streaming. Per step: write own gates
//     in-place into G (own rows), threadfence + per-(b,t) atomic arrival counter,
//     spin to 4, all blocks redundantly compute c/h update (4KB gate read from L2).
//     Fresh counter+rows per t => no reset/stale-L1 hazards; 256 blocks all
//     co-resident (LDS 69KB, 1 blk/CU) => no spin deadlock. Ascending-k4 accum
//     unchanged => bit-identical (absmax is the race canary).
// R17: R16 bench timed out at GPU acquisition (never ran) — resubmitted unchanged.
// All f32 (precision requirement established R1/R2: argmax needs exact-ish logits).

#define T_ 64
#define B_ 64
#define NTB 4096
#define HID 256
#define G4 1024

typedef float f4 __attribute__((ext_vector_type(4)));

// XOR swizzle for LDS float4 slot j -> float column index (injective, 16B aligned)
#define XS(j) ((((j) << 2)) ^ ((((j) >> 3) & 7) << 2))

__device__ inline float sigm(float x) { return 1.f / (1.f + __expf(-x)); }
__device__ inline float tanh_(float x) { return 1.f - 2.f / (1.f + __expf(2.f * x)); }
__device__ inline float elu_(float x) { return x > 0.f ? x : __expf(x) - 1.f; }

// ---------------- prep: weight relayouts (all f32) ----------------
__global__ void k_prep(const float* __restrict__ wih0, const float* __restrict__ wih1,
                       const float* __restrict__ whh0, const float* __restrict__ whh1,
                       const float* __restrict__ cw2, const float* __restrict__ cw3,
                       const float* __restrict__ cw4, const float* __restrict__ pw,
                       const float* __restrict__ bw,
                       float* __restrict__ wih0T, float* __restrict__ wih1T,
                       float* __restrict__ wq0, float* __restrict__ wq1,
                       float* __restrict__ wc2, float* __restrict__ wc3,
                       float* __restrict__ wc4, float* __restrict__ pwT) {
  int idx = blockIdx.x * 256 + threadIdx.x;
  if (idx < 294912) {                       // wih0T[k*1024+j] = wih0[j*288+k]
    int k = idx >> 10, j = idx & 1023;
    wih0T[idx] = wih0[j * 288 + k];
  } else if (idx < 557056) {                // wih1T[k*1024+j] = wih1[j*256+k]
    int r = idx - 294912; int k = r >> 10, j = r & 1023;
    wih1T[r] = wih1[j * 256 + k];
  } else if (idx < 819200) {                // wq0[(k4*1024+row)*4+c] = whh0[row][4k4+c]
    int r = idx - 557056;
    int cc = r & 3, row = (r >> 2) & 1023, k4 = r >> 12;
    wq0[r] = whh0[row * 256 + k4 * 4 + cc];
  } else if (idx < 1081344) {
    int r = idx - 819200;
    int cc = r & 3, row = (r >> 2) & 1023, k4 = r >> 12;
    wq1[r] = whh1[row * 256 + k4 * 4 + cc];
  } else if (idx < 1108992) {               // conv weights -> [o][tap][i] f32
    int r = idx - 1081344;                  // 3 * 9216
    int which = r / 9216; int d = r - which * 9216;
    int i = d & 31, tap = (d >> 5) % 9, o = d / 288;
    int kh = tap / 3, kw = tap - kh * 3;
    const float* src = which == 0 ? cw2 : (which == 1 ? cw3 : cw4);
    float* dst = which == 0 ? wc2 : (which == 1 ? wc3 : wc4);
    dst[d] = src[((o * 32 + i) * 3 + kh) * 3 + kw];
  } else if (idx < 1113088) {               // pwT[k*16+o]: policy rows 0..11, baseline row 12
    int r = idx - 1108992; int k = r >> 4, o = r & 15;
    pwT[r] = o < 12 ? pw[o * 256 + k] : (o == 12 ? bw[k] : 0.f);
  }
}

// ---------------- done -> notdone float, robust to encoding (verified) ----------------
__global__ __launch_bounds__(1024)
void k_donecvt(const unsigned char* __restrict__ db, float* __restrict__ nd) {
  int tid = threadIdx.x;
  const unsigned* dw = (const unsigned*)db;
  unsigned w = dw[tid];
  int odd = ((w & 0xFFFFFF00u) != 0u && w != 0x3F800000u) ? 1 : 0;
  int any = __syncthreads_count(odd);
  bool u8 = (any > 0);
  for (int j = tid; j < 4096; j += 1024) {
    unsigned v = u8 ? (unsigned)db[j] : dw[j];
    nd[j] = v ? 0.f : 1.f;
  }
}

// ---------------- FUSED conv1..conv4: frame[n] -> featT[k][n'] (n' = b*64+t) ----------
// R11-exact structure. LDS 79872B -> 2 blk/CU. launch_bounds(512,8): VGPR 56 measured.
__global__ __launch_bounds__(512, 8)
void k_convall(const float* __restrict__ frame, const float* __restrict__ cw1,
               const float* __restrict__ cb1, const float* __restrict__ wc2,
               const float* __restrict__ cb2, const float* __restrict__ wc3,
               const float* __restrict__ cb3, const float* __restrict__ wc4,
               const float* __restrict__ cb4, float* __restrict__ featT) {
  __shared__ __align__(16) float a1t[8][1792];   // conv1 out: [oq][swizzled 441 pos x4]
  __shared__ __align__(16) float act2l[8][512];  // conv2 out: [oq][swizzled 121 pos x4]
  __shared__ __align__(16) float act3l[8][192];  // conv3 out: [oq][swizzled 36 pos x4]
  int n = blockIdx.x;
  int tid = threadIdx.x;
  const float4* fp = (const float4*)(frame + (size_t)n * 7056);
  int ncol = ((n & 63) << 6) | (n >> 6);         // b*64+t layout for downstream

  // ---- stage B: conv1 (frame direct from global, L1-cached 9x reuse) ----
  if (tid < 441) {
    int p = tid / 21, q = tid - (tid / 21) * 21;
    float px[9][4];
#pragma unroll
    for (int kh = 0; kh < 3; ++kh) {
#pragma unroll
      for (int kw = 0; kw < 3; ++kw) {
        int A = 2 * p - 1 + kh, Bc = 2 * q - 1 + kw;
        bool ok = ((unsigned)A < 42u) && ((unsigned)Bc < 42u);
        float4 v = ok ? fp[Bc * 42 + A] : make_float4(0.f, 0.f, 0.f, 0.f);
        px[kh * 3 + kw][0] = v.x; px[kh * 3 + kw][1] = v.y;
        px[kh * 3 + kw][2] = v.z; px[kh * 3 + kw][3] = v.w;
      }
    }
    int col = XS(tid);
#pragma unroll
    for (int oq = 0; oq < 8; ++oq) {
      float4 acc;
      float* ap = (float*)&acc;
#pragma unroll
      for (int j = 0; j < 4; ++j) {
        int o = oq * 4 + j;
        float a = cb1[o];
        const float* w = cw1 + o * 36;           // [c][kh][kw], scalar s_load
#pragma unroll
        for (int tap = 0; tap < 9; ++tap)
          a += px[tap][0] * w[tap] + px[tap][1] * w[9 + tap] +
               px[tap][2] * w[18 + tap] + px[tap][3] * w[27 + tap];
        ap[j] = elu_(a);
      }
      *(float4*)&a1t[oq][col] = acc;
    }
  }
  __syncthreads();

  // ---- stage C: conv2 (21x21x32 -> 11x11x32), thread = (pos, o-octet) ----
  {
    int s = tid & 127, oh = tid >> 7;            // oh 0..3, wave-uniform
    int ob = __builtin_amdgcn_readfirstlane(oh << 3);
    if (s < 121) {
      int p = s / 11, q = s - (s / 11) * 11;
      float acc[8];
#pragma unroll
      for (int oi = 0; oi < 8; ++oi) acc[oi] = cb2[ob + oi];
#pragma unroll
      for (int kh = 0; kh < 3; ++kh) {
        int A = 2 * p - 1 + kh;
        if ((unsigned)A >= 21u) continue;
#pragma unroll
        for (int kw = 0; kw < 3; ++kw) {
          int Bc = 2 * q - 1 + kw;
          if ((unsigned)Bc >= 21u) continue;
          int pos = A * 21 + Bc;
          int col = XS(pos);
          int tap = kh * 3 + kw;
#pragma unroll
          for (int i4 = 0; i4 < 8; ++i4) {
            float4 v = *(const float4*)&a1t[i4][col];
#pragma unroll
            for (int oi = 0; oi < 8; ++oi) {
              const float* w = wc2 + ((ob + oi) * 9 + tap) * 32 + i4 * 4;  // s_load
              acc[oi] += v.x * w[0] + v.y * w[1] + v.z * w[2] + v.w * w[3];
            }
          }
        }
      }
      int colw = XS(s);
#pragma unroll
      for (int half = 0; half < 2; ++half) {
        float4 o4 = make_float4(elu_(acc[half * 4 + 0]), elu_(acc[half * 4 + 1]),
                                elu_(acc[half * 4 + 2]), elu_(acc[half * 4 + 3]));
        *(float4*)&act2l[(ob >> 2) + half][colw] = o4;
      }
    }
  }
  __syncthreads();

  // ---- stage D: conv3 (11x11x32 -> 6x6x32), wave = o-quad, lanes = 36 pos ----
  {
    int wv = tid >> 6, lane = tid & 63;
    int oq = __builtin_amdgcn_readfirstlane(wv);
    if (lane < 36) {
      int p = lane / 6, q = lane - (lane / 6) * 6;
      float acc[4];
#pragma unroll
      for (int j = 0; j < 4; ++j) acc[j] = cb3[oq * 4 + j];
#pragma unroll
      for (int kh = 0; kh < 3; ++kh) {
        int A = 2 * p - 1 + kh;
        if ((unsigned)A >= 11u) continue;
#pragma unroll
        for (int kw = 0; kw < 3; ++kw) {
          int Bc = 2 * q - 1 + kw;
          if ((unsigned)Bc >= 11u) continue;
          int col = XS(A * 11 + Bc);
          int tap = kh * 3 + kw;
#pragma unroll
          for (int i4 = 0; i4 < 8; ++i4) {
            float4 v = *(const float4*)&act2l[i4][col];
#pragma unroll
            for (int j = 0; j < 4; ++j) {
              const float* w = wc3 + ((oq * 4 + j) * 9 + tap) * 32 + i4 * 4;  // s_load
              acc[j] += v.x * w[0] + v.y * w[1] + v.z * w[2] + v.w * w[3];
            }
          }
        }
      }
      float4 o4 = make_float4(elu_(acc[0]), elu_(acc[1]), elu_(acc[2]), elu_(acc[3]));
      *(float4*)&act3l[oq][XS(p * 6 + q)] = o4;
    }
  }
  __syncthreads();

  // ---- stage E: conv4 (6x6x32 -> 3x3x32), wave = o-quad, lanes = 9 pos; featT out ----
  {
    int wv = tid >> 6, lane = tid & 63;
    int oq = __builtin_amdgcn_readfirstlane(wv);
    if (lane < 9) {
      int p = lane / 3, q = lane - (lane / 3) * 3;
      float acc[4];
#pragma unroll
      for (int j = 0; j < 4; ++j) acc[j] = cb4[oq * 4 + j];
#pragma unroll
      for (int kh = 0; kh < 3; ++kh) {
        int A = 2 * p - 1 + kh;
        if ((unsigned)A >= 6u) continue;
#pragma unroll
        for (int kw = 0; kw < 3; ++kw) {
          int Bc = 2 * q - 1 + kw;
          if ((unsigned)Bc >= 6u) continue;
          int col = XS(A * 6 + Bc);
          int tap = kh * 3 + kw;
#pragma unroll
          for (int i4 = 0; i4 < 8; ++i4) {
            float4 v = *(const float4*)&act3l[i4][col];
#pragma unroll
            for (int j = 0; j < 4; ++j) {
              const float* w = wc4 + ((oq * 4 + j) * 9 + tap) * 32 + i4 * 4;  // s_load
              acc[j] += v.x * w[0] + v.y * w[1] + v.z * w[2] + v.w * w[3];
            }
          }
        }
      }
#pragma unroll
      for (int j = 0; j < 4; ++j)                // feat k = c*9 + p*3 + q
        featT[(size_t)((oq * 4 + j) * 9 + lane) * 4096 + ncol] = elu_(acc[j]);
    }
  }
}

// ---------------- GEMM on transposed input: out[n][j] = sum_k inT[k][n]*wT[k][j] + b ----
__global__ __launch_bounds__(256)
void k_gemm2(const float* __restrict__ inT, const float* __restrict__ wT,
             const float* __restrict__ b1, const float* __restrict__ b2,
             float* __restrict__ out, int K) {
  int nb = blockIdx.x >> 4, jb = blockIdx.x & 15;
  int lane = threadIdx.x & 63, wv = threadIdx.x >> 6;
  int n = nb * 64 + lane;
  int j0 = jb * 64 + __builtin_amdgcn_readfirstlane(wv << 4);
  float acc[16];
#pragma unroll
  for (int m = 0; m < 16; ++m) acc[m] = 0.f;
  const float* ip = inT + n;
#pragma unroll 4
  for (int k = 0; k < K; ++k) {
    float x = ip[(size_t)k * 4096];
    const float* w = wT + k * 1024 + j0;         // wave-uniform -> s_load x16
#pragma unroll
    for (int m = 0; m < 16; ++m) acc[m] += x * w[m];
  }
  float* op = out + (size_t)n * 1024 + j0;
#pragma unroll
  for (int h = 0; h < 4; ++h) {
    float4 o4 = make_float4(acc[h * 4 + 0] + b1[j0 + h * 4 + 0] + b2[j0 + h * 4 + 0],
                            acc[h * 4 + 1] + b1[j0 + h * 4 + 1] + b2[j0 + h * 4 + 1],
                            acc[h * 4 + 2] + b1[j0 + h * 4 + 2] + b2[j0 + h * 4 + 2],
                            acc[h * 4 + 3] + b1[j0 + h * 4 + 3] + b2[j0 + h * 4 + 3]);
    *(float4*)&op[h * 4] = o4;
  }
}

// ---------------- persistent LSTM scan: 4 blocks per batch elem ----------------
// grid 256 = (b = bid&63, qd = bid>>6). Block owns gate rows [qd*256, qd*256+256).
// W_hh rows fully resident: 48 reg quads (192 VGPR, 1 wave/SIMD) + 16 LDS quads (64KB).
// Per step: gates written IN PLACE into G (own rows; fresh row per t) -> fence ->
// per-(b,t) atomic arrival counter -> spin to 4 -> redundant full c/h update in every
// block. Stale-L1 safe: every cross-block address touched once per launch. Ascending
// k4 accumulation -> bit-identical to R15 scan.
#define WR48(X) X(0) X(1) X(2) X(3) X(4) X(5) X(6) X(7) X(8) X(9) X(10) X(11) \
  X(12) X(13) X(14) X(15) X(16) X(17) X(18) X(19) X(20) X(21) X(22) X(23) \
  X(24) X(25) X(26) X(27) X(28) X(29) X(30) X(31) X(32) X(33) X(34) X(35) \
  X(36) X(37) X(38) X(39) X(40) X(41) X(42) X(43) X(44) X(45) X(46) X(47)

__global__ __launch_bounds__(256)
void k_scan4(const float* __restrict__ wq, float* __restrict__ G,
             const float* __restrict__ h_init, const float* __restrict__ c_init,
             const float* __restrict__ ndb, int* __restrict__ af,
             float* __restrict__ h_allT, float* __restrict__ hT,
             float* __restrict__ cT) {
  int bid = blockIdx.x;
  int b = bid & 63, qd = bid >> 6;
  int tid = threadIdx.x;
  int r = qd * 256 + tid;                        // owned gate row
  __shared__ __align__(16) float hs[256];
  __shared__ __align__(16) f4 wl[16][256];       // 65536 B
  __shared__ __align__(16) float hbuf[16][64];   // 4096 B
  const f4* wq4 = (const f4*)wq;                 // wq4[k4*1024 + row]
#define DECLR(i) f4 wr##i = wq4[(i) * 1024 + r];
  WR48(DECLR)
#undef DECLR
#pragma unroll
  for (int q = 0; q < 16; ++q) wl[q][tid] = wq4[(48 + q) * 1024 + r];
  hs[tid] = h_init[b * HID + tid];
  float c = c_init[b * HID + tid];
  float hlast = 0.f;
  __syncthreads();
  const f4* hs4 = (const f4*)hs;
  float* gpb = G + (size_t)b * 65536;            // rows n' = b*64+t
  int* flag = af + b * 64;
  for (int t = 0; t < T_; ++t) {
    float nd = ndb[t * B_ + b];
    f4 acc = {0.f, 0.f, 0.f, 0.f};
#define FMAR(i) { f4 h4 = hs4[i]; acc += h4 * wr##i; }
    WR48(FMAR)
#undef FMAR
#pragma unroll
    for (int q = 0; q < 16; ++q) { f4 h4 = hs4[48 + q]; acc += h4 * wl[q][tid]; }
    float* grow = gpb + (size_t)t * 1024;
    float g = grow[r] + (acc.x + acc.y + acc.z + acc.w) * nd;
    grow[r] = g;                                 // in-place: own rows only
    __threadfence();                             // flush each thread's store (device)
    __syncthreads();                             // all stores+fences before signal
    if (tid == 0) {
      atomicAdd(flag + t, 1);                    // device-scope arrival
      while (__hip_atomic_load(flag + t, __ATOMIC_ACQUIRE,
                               __HIP_MEMORY_SCOPE_AGENT) < 4) {}
    }
    __syncthreads();                             // all threads see 4-arrival
    float gi = grow[tid], gf = grow[tid + 256];
    float gg = grow[tid + 512], go = grow[tid + 768];
    c = sigm(gf) * (c * nd) + sigm(gi) * tanh_(gg);
    float h = sigm(go) * tanh_(c);
    hs[tid] = h;
    hlast = h;
    if ((tid >> 6) == qd) hbuf[t & 15][tid & 63] = h;
    __syncthreads();                             // hs/hbuf ready
    if ((t & 15) == 15) {                        // flush 16-step tile (own 64 rows)
      int jrl = tid >> 2, quad = tid & 3, t0 = t & ~15;
      float4 o4 = make_float4(hbuf[quad * 4 + 0][jrl], hbuf[quad * 4 + 1][jrl],
                              hbuf[quad * 4 + 2][jrl], hbuf[quad * 4 + 3][jrl]);
      *(float4*)&h_allT[(size_t)(qd * 64 + jrl) * 4096 + b * 64 + t0 + quad * 4] = o4;
    }
  }
  if (qd == 0) { hT[b * HID + tid] = hlast; cT[b * HID + tid] = c; }
}

// ---------------- heads + argmax (merged): thread = output row n = t*64+b ----------
// h1aT columns are b*64+t -> col = (n&63)*64 + (n>>6).
__global__ __launch_bounds__(256)
void k_heads(const float* __restrict__ h1aT, const float* __restrict__ pwT,
             const float* __restrict__ pb, const float* __restrict__ bb,
             float* __restrict__ out) {
  int n = blockIdx.x * 256 + threadIdx.x;
  int col = ((n & 63) << 6) | (n >> 6);
  float acc[13];
#pragma unroll
  for (int o = 0; o < 12; ++o) acc[o] = pb[o];
  acc[12] = bb[0];
  for (int k = 0; k < 256; ++k) {
    float h = h1aT[(size_t)k * 4096 + col];
    const float* w = pwT + k * 16;               // uniform -> s_load
#pragma unroll
    for (int o = 0; o < 13; ++o) acc[o] += h * w[o];
  }
  float best = acc[0]; int bi = 0;
#pragma unroll
  for (int o = 1; o < 12; ++o)
    if (acc[o] > best) { best = acc[o]; bi = o; }   // strict > == first-max-wins
#pragma unroll
  for (int o = 0; o < 12; ++o) out[n * 12 + o] = acc[o];
  out[49152 + n] = acc[12];
  out[53248 + n] = (float)bi;
}

extern "C" void kernel_launch(void* const* d_in, const int* in_sizes, int n_in,
                              void* d_out, int out_size, void* d_ws, size_t ws_size,
                              hipStream_t stream) {
  const float* frame = (const float*)d_in[0];
  const unsigned char* done = (const unsigned char*)d_in[1];
  const float* h0 = (const float*)d_in[2];
  const float* c0 = (const float*)d_in[3];
  const float* cw1 = (const float*)d_in[4];  const float* cb1 = (const float*)d_in[5];
  const float* cw2 = (const float*)d_in[6];  const float* cb2 = (const float*)d_in[7];
  const float* cw3 = (const float*)d_in[8];  const float* cb3 = (const float*)d_in[9];
  const float* cw4 = (const float*)d_in[10]; const float* cb4 = (const float*)d_in[11];
  const float* wih0 = (const float*)d_in[12]; const float* whh0 = (const float*)d_in[13];
  const float* bih0 = (const float*)d_in[14]; const float* bhh0 = (const float*)d_in[15];
  const float* wih1 = (const float*)d_in[16]; const float* whh1 = (const float*)d_in[17];
  const float* bih1 = (const float*)d_in[18]; const float* bhh1 = (const float*)d_in[19];
  const float* pw = (const float*)d_in[20]; const float* pb = (const float*)d_in[21];
  const float* bw = (const float*)d_in[22]; const float* bb = (const float*)d_in[23];

  // workspace layout (~51 MB + 32KB flags, all f32)
  float* featT = (float*)d_ws;                      //  1,179,648  [288][4096]
  float* G0    = featT + 1179648;                   //  4,194,304
  float* G1    = G0 + 4194304;                      //  4,194,304
  float* h0aT  = G1 + 4194304;                      //  1,048,576  [256][4096]
  float* h1aT  = h0aT + 1048576;                    //  1,048,576
  float* wih0T = h1aT + 1048576;                    //    294,912
  float* wih1T = wih0T + 294912;                    //    262,144
  float* wq0   = wih1T + 262144;                    //    262,144  whh0 quad layout
  float* wq1   = wq0 + 262144;                      //    262,144  whh1 quad layout
  float* wc2   = wq1 + 262144;                      //      9,216
  float* wc3   = wc2 + 9216;
  float* wc4   = wc3 + 9216;
  float* pwT   = wc4 + 9216;                        //      4,096
  float* ndb   = pwT + 4096;                        //      4,096
  int*   af    = (int*)(ndb + 4096);                //      8,192 ints (2 layers)

  float* out = (float*)d_out;
  float* o_hT = out + 57344;
  float* o_cT = out + 90112;

  hipMemsetAsync(af, 0, 8192 * sizeof(int), stream);   // fresh arrival counters
  k_prep<<<4348, 256, 0, stream>>>(wih0, wih1, whh0, whh1, cw2, cw3, cw4, pw, bw,
                                   wih0T, wih1T, wq0, wq1, wc2, wc3, wc4, pwT);
  k_donecvt<<<1, 1024, 0, stream>>>(done, ndb);
  k_convall<<<4096, 512, 0, stream>>>(frame, cw1, cb1, wc2, cb2, wc3, cb3, wc4, cb4,
                                      featT);
  k_gemm2<<<1024, 256, 0, stream>>>(featT, wih0T, bih0, bhh0, G0, 288);
  k_scan4<<<256, 256, 0, stream>>>(wq0, G0, h0, c0, ndb, af, h0aT, o_hT, o_cT);
  k_gemm2<<<1024, 256, 0, stream>>>(h0aT, wih1T, bih1, bhh1, G1, 256);
  k_scan4<<<256, 256, 0, stream>>>(wq1, G1, h0 + 16384, c0 + 16384, ndb, af + 4096,
                                   h1aT, o_hT + 16384, o_cT + 16384);
  k_heads<<<16, 256, 0, stream>>>(h1aT, pwT, pb, bb, out);
}

// Round 15
// 1696.511 us; speedup vs baseline: 1.9847x; 1.9847x over previous
//
#include <hip/hip_runtime.h>
#include <hip/hip_bf16.h>

// MarioDoomPolicyNet: conv stack (4x stride-2 + ELU) -> 2-layer LSTM scan -> heads.
// R11/R12: convall 577us (VGPR 56); total 1706.5. R15: b*64+t layout + scan write
//     tiling, 1712.3 (tied-best; convall WRITE 36.8->4.8MB).
// R13/R14: split-half conv DEAD (spill / 2x issue).
// R16: persistent scan4 FAILED measured (3367): compiler capped VGPR at 128 ->
//     scratch spill, 1 blk/CU, VALUBusy 2%. R18 (launch_bounds(256,1) fix) timed
//     out at GPU acquisition FOUR times (R11-R14 of session 2) — abandoned per
//     pre-commitment + broker saturation; consolidating on verified R15 base.
// R21: R15-exact + scan residency bump: named reg quads 16->18 (+8 VGPR, est base
//     ~90, cap 128 @ 4 waves/SIMD), LDS quads = 18..25, streamed 40->38. Scan is
//     L2-port-bound on streamed quads (~8us/step @ 640KB) -> -5% streaming.
//     Ascending-k4 accumulation unchanged -> bit-identical (absmax canary 0.0078125).
// All f32 (precision requirement established R1/R2: argmax needs exact-ish logits).

#define T_ 64
#define B_ 64
#define NTB 4096
#define HID 256
#define G4 1024

typedef float f4 __attribute__((ext_vector_type(4)));

// XOR swizzle for LDS float4 slot j -> float column index (injective, 16B aligned)
#define XS(j) ((((j) << 2)) ^ ((((j) >> 3) & 7) << 2))

__device__ inline float sigm(float x) { return 1.f / (1.f + __expf(-x)); }
__device__ inline float tanh_(float x) { return 1.f - 2.f / (1.f + __expf(2.f * x)); }
__device__ inline float elu_(float x) { return x > 0.f ? x : __expf(x) - 1.f; }

// ---------------- prep: weight relayouts (all f32) ----------------
__global__ void k_prep(const float* __restrict__ wih0, const float* __restrict__ wih1,
                       const float* __restrict__ whh0, const float* __restrict__ whh1,
                       const float* __restrict__ cw2, const float* __restrict__ cw3,
                       const float* __restrict__ cw4, const float* __restrict__ pw,
                       const float* __restrict__ bw,
                       float* __restrict__ wih0T, float* __restrict__ wih1T,
                       float* __restrict__ wq0, float* __restrict__ wq1,
                       float* __restrict__ wc2, float* __restrict__ wc3,
                       float* __restrict__ wc4, float* __restrict__ pwT) {
  int idx = blockIdx.x * 256 + threadIdx.x;
  if (idx < 294912) {                       // wih0T[k*1024+j] = wih0[j*288+k]
    int k = idx >> 10, j = idx & 1023;
    wih0T[idx] = wih0[j * 288 + k];
  } else if (idx < 557056) {                // wih1T[k*1024+j] = wih1[j*256+k]
    int r = idx - 294912; int k = r >> 10, j = r & 1023;
    wih1T[r] = wih1[j * 256 + k];
  } else if (idx < 819200) {                // wq0[(k4*1024+row)*4+c] = whh0[row][4k4+c]
    int r = idx - 557056;
    int cc = r & 3, row = (r >> 2) & 1023, k4 = r >> 12;
    wq0[r] = whh0[row * 256 + k4 * 4 + cc];
  } else if (idx < 1081344) {
    int r = idx - 819200;
    int cc = r & 3, row = (r >> 2) & 1023, k4 = r >> 12;
    wq1[r] = whh1[row * 256 + k4 * 4 + cc];
  } else if (idx < 1108992) {               // conv weights -> [o][tap][i] f32
    int r = idx - 1081344;                  // 3 * 9216
    int which = r / 9216; int d = r - which * 9216;
    int i = d & 31, tap = (d >> 5) % 9, o = d / 288;
    int kh = tap / 3, kw = tap - kh * 3;
    const float* src = which == 0 ? cw2 : (which == 1 ? cw3 : cw4);
    float* dst = which == 0 ? wc2 : (which == 1 ? wc3 : wc4);
    dst[d] = src[((o * 32 + i) * 3 + kh) * 3 + kw];
  } else if (idx < 1113088) {               // pwT[k*16+o]: policy rows 0..11, baseline row 12
    int r = idx - 1108992; int k = r >> 4, o = r & 15;
    pwT[r] = o < 12 ? pw[o * 256 + k] : (o == 12 ? bw[k] : 0.f);
  }
}

// ---------------- done -> notdone float, robust to encoding (verified) ----------------
__global__ __launch_bounds__(1024)
void k_donecvt(const unsigned char* __restrict__ db, float* __restrict__ nd) {
  int tid = threadIdx.x;
  const unsigned* dw = (const unsigned*)db;
  unsigned w = dw[tid];
  int odd = ((w & 0xFFFFFF00u) != 0u && w != 0x3F800000u) ? 1 : 0;
  int any = __syncthreads_count(odd);
  bool u8 = (any > 0);
  for (int j = tid; j < 4096; j += 1024) {
    unsigned v = u8 ? (unsigned)db[j] : dw[j];
    nd[j] = v ? 0.f : 1.f;
  }
}

// ---------------- FUSED conv1..conv4: frame[n] -> featT[k][n'] (n' = b*64+t) ----------
// R11-exact structure. LDS 79872B -> 2 blk/CU. launch_bounds(512,8): VGPR 56 measured.
__global__ __launch_bounds__(512, 8)
void k_convall(const float* __restrict__ frame, const float* __restrict__ cw1,
               const float* __restrict__ cb1, const float* __restrict__ wc2,
               const float* __restrict__ cb2, const float* __restrict__ wc3,
               const float* __restrict__ cb3, const float* __restrict__ wc4,
               const float* __restrict__ cb4, float* __restrict__ featT) {
  __shared__ __align__(16) float a1t[8][1792];   // conv1 out: [oq][swizzled 441 pos x4]
  __shared__ __align__(16) float act2l[8][512];  // conv2 out: [oq][swizzled 121 pos x4]
  __shared__ __align__(16) float act3l[8][192];  // conv3 out: [oq][swizzled 36 pos x4]
  int n = blockIdx.x;
  int tid = threadIdx.x;
  const float4* fp = (const float4*)(frame + (size_t)n * 7056);
  int ncol = ((n & 63) << 6) | (n >> 6);         // b*64+t layout for downstream

  // ---- stage B: conv1 (frame direct from global, L1-cached 9x reuse) ----
  if (tid < 441) {
    int p = tid / 21, q = tid - (tid / 21) * 21;
    float px[9][4];
#pragma unroll
    for (int kh = 0; kh < 3; ++kh) {
#pragma unroll
      for (int kw = 0; kw < 3; ++kw) {
        int A = 2 * p - 1 + kh, Bc = 2 * q - 1 + kw;
        bool ok = ((unsigned)A < 42u) && ((unsigned)Bc < 42u);
        float4 v = ok ? fp[Bc * 42 + A] : make_float4(0.f, 0.f, 0.f, 0.f);
        px[kh * 3 + kw][0] = v.x; px[kh * 3 + kw][1] = v.y;
        px[kh * 3 + kw][2] = v.z; px[kh * 3 + kw][3] = v.w;
      }
    }
    int col = XS(tid);
#pragma unroll
    for (int oq = 0; oq < 8; ++oq) {
      float4 acc;
      float* ap = (float*)&acc;
#pragma unroll
      for (int j = 0; j < 4; ++j) {
        int o = oq * 4 + j;
        float a = cb1[o];
        const float* w = cw1 + o * 36;           // [c][kh][kw], scalar s_load
#pragma unroll
        for (int tap = 0; tap < 9; ++tap)
          a += px[tap][0] * w[tap] + px[tap][1] * w[9 + tap] +
               px[tap][2] * w[18 + tap] + px[tap][3] * w[27 + tap];
        ap[j] = elu_(a);
      }
      *(float4*)&a1t[oq][col] = acc;
    }
  }
  __syncthreads();

  // ---- stage C: conv2 (21x21x32 -> 11x11x32), thread = (pos, o-octet) ----
  {
    int s = tid & 127, oh = tid >> 7;            // oh 0..3, wave-uniform
    int ob = __builtin_amdgcn_readfirstlane(oh << 3);
    if (s < 121) {
      int p = s / 11, q = s - (s / 11) * 11;
      float acc[8];
#pragma unroll
      for (int oi = 0; oi < 8; ++oi) acc[oi] = cb2[ob + oi];
#pragma unroll
      for (int kh = 0; kh < 3; ++kh) {
        int A = 2 * p - 1 + kh;
        if ((unsigned)A >= 21u) continue;
#pragma unroll
        for (int kw = 0; kw < 3; ++kw) {
          int Bc = 2 * q - 1 + kw;
          if ((unsigned)Bc >= 21u) continue;
          int pos = A * 21 + Bc;
          int col = XS(pos);
          int tap = kh * 3 + kw;
#pragma unroll
          for (int i4 = 0; i4 < 8; ++i4) {
            float4 v = *(const float4*)&a1t[i4][col];
#pragma unroll
            for (int oi = 0; oi < 8; ++oi) {
              const float* w = wc2 + ((ob + oi) * 9 + tap) * 32 + i4 * 4;  // s_load
              acc[oi] += v.x * w[0] + v.y * w[1] + v.z * w[2] + v.w * w[3];
            }
          }
        }
      }
      int colw = XS(s);
#pragma unroll
      for (int half = 0; half < 2; ++half) {
        float4 o4 = make_float4(elu_(acc[half * 4 + 0]), elu_(acc[half * 4 + 1]),
                                elu_(acc[half * 4 + 2]), elu_(acc[half * 4 + 3]));
        *(float4*)&act2l[(ob >> 2) + half][colw] = o4;
      }
    }
  }
  __syncthreads();

  // ---- stage D: conv3 (11x11x32 -> 6x6x32), wave = o-quad, lanes = 36 pos ----
  {
    int wv = tid >> 6, lane = tid & 63;
    int oq = __builtin_amdgcn_readfirstlane(wv);
    if (lane < 36) {
      int p = lane / 6, q = lane - (lane / 6) * 6;
      float acc[4];
#pragma unroll
      for (int j = 0; j < 4; ++j) acc[j] = cb3[oq * 4 + j];
#pragma unroll
      for (int kh = 0; kh < 3; ++kh) {
        int A = 2 * p - 1 + kh;
        if ((unsigned)A >= 11u) continue;
#pragma unroll
        for (int kw = 0; kw < 3; ++kw) {
          int Bc = 2 * q - 1 + kw;
          if ((unsigned)Bc >= 11u) continue;
          int col = XS(A * 11 + Bc);
          int tap = kh * 3 + kw;
#pragma unroll
          for (int i4 = 0; i4 < 8; ++i4) {
            float4 v = *(const float4*)&act2l[i4][col];
#pragma unroll
            for (int j = 0; j < 4; ++j) {
              const float* w = wc3 + ((oq * 4 + j) * 9 + tap) * 32 + i4 * 4;  // s_load
              acc[j] += v.x * w[0] + v.y * w[1] + v.z * w[2] + v.w * w[3];
            }
          }
        }
      }
      float4 o4 = make_float4(elu_(acc[0]), elu_(acc[1]), elu_(acc[2]), elu_(acc[3]));
      *(float4*)&act3l[oq][XS(p * 6 + q)] = o4;
    }
  }
  __syncthreads();

  // ---- stage E: conv4 (6x6x32 -> 3x3x32), wave = o-quad, lanes = 9 pos; featT out ----
  {
    int wv = tid >> 6, lane = tid & 63;
    int oq = __builtin_amdgcn_readfirstlane(wv);
    if (lane < 9) {
      int p = lane / 3, q = lane - (lane / 3) * 3;
      float acc[4];
#pragma unroll
      for (int j = 0; j < 4; ++j) acc[j] = cb4[oq * 4 + j];
#pragma unroll
      for (int kh = 0; kh < 3; ++kh) {
        int A = 2 * p - 1 + kh;
        if ((unsigned)A >= 6u) continue;
#pragma unroll
        for (int kw = 0; kw < 3; ++kw) {
          int Bc = 2 * q - 1 + kw;
          if ((unsigned)Bc >= 6u) continue;
          int col = XS(A * 6 + Bc);
          int tap = kh * 3 + kw;
#pragma unroll
          for (int i4 = 0; i4 < 8; ++i4) {
            float4 v = *(const float4*)&act3l[i4][col];
#pragma unroll
            for (int j = 0; j < 4; ++j) {
              const float* w = wc4 + ((oq * 4 + j) * 9 + tap) * 32 + i4 * 4;  // s_load
              acc[j] += v.x * w[0] + v.y * w[1] + v.z * w[2] + v.w * w[3];
            }
          }
        }
      }
#pragma unroll
      for (int j = 0; j < 4; ++j)                // feat k = c*9 + p*3 + q
        featT[(size_t)((oq * 4 + j) * 9 + lane) * 4096 + ncol] = elu_(acc[j]);
    }
  }
}

// ---------------- GEMM on transposed input: out[n][j] = sum_k inT[k][n]*wT[k][j] + b ----
__global__ __launch_bounds__(256)
void k_gemm2(const float* __restrict__ inT, const float* __restrict__ wT,
             const float* __restrict__ b1, const float* __restrict__ b2,
             float* __restrict__ out, int K) {
  int nb = blockIdx.x >> 4, jb = blockIdx.x & 15;
  int lane = threadIdx.x & 63, wv = threadIdx.x >> 6;
  int n = nb * 64 + lane;
  int j0 = jb * 64 + __builtin_amdgcn_readfirstlane(wv << 4);
  float acc[16];
#pragma unroll
  for (int m = 0; m < 16; ++m) acc[m] = 0.f;
  const float* ip = inT + n;
#pragma unroll 4
  for (int k = 0; k < K; ++k) {
    float x = ip[(size_t)k * 4096];
    const float* w = wT + k * 1024 + j0;         // wave-uniform -> s_load x16
#pragma unroll
    for (int m = 0; m < 16; ++m) acc[m] += x * w[m];
  }
  float* op = out + (size_t)n * 1024 + j0;
#pragma unroll
  for (int h = 0; h < 4; ++h) {
    float4 o4 = make_float4(acc[h * 4 + 0] + b1[j0 + h * 4 + 0] + b2[j0 + h * 4 + 0],
                            acc[h * 4 + 1] + b1[j0 + h * 4 + 1] + b2[j0 + h * 4 + 1],
                            acc[h * 4 + 2] + b1[j0 + h * 4 + 2] + b2[j0 + h * 4 + 2],
                            acc[h * 4 + 3] + b1[j0 + h * 4 + 3] + b2[j0 + h * 4 + 3]);
    *(float4*)&op[h * 4] = o4;
  }
}

// ---------------- LSTM scan (one layer): 64 WGs, 1 batch elem each ----------------
// Hybrid-resident W_hh (R21 split): 18 reg quads (k4 0-17) + 8 LDS quads (18-25) +
// 38 streamed (26-63). Ascending k4 order -> bit-identical to R15.
// G rows are n' = b*64+t (gp = G + b*65536 + j, step stride 1024). h buffered in
// LDS hbuf[16][256], flushed every 16 steps as full 64B lines (R15 write fix).
#define WREGS(X) X(0) X(1) X(2) X(3) X(4) X(5) X(6) X(7) \
                 X(8) X(9) X(10) X(11) X(12) X(13) X(14) X(15) X(16) X(17)

__global__ __launch_bounds__(1024, 4)
void k_scan(const float* __restrict__ wq, const float* __restrict__ G,
            const float* __restrict__ h_init, const float* __restrict__ c_init,
            const float* __restrict__ ndb, float* __restrict__ h_allT,
            float* __restrict__ hT, float* __restrict__ cT) {
  int b = blockIdx.x, j = threadIdx.x;
  __shared__ __align__(16) float hs[256];
  __shared__ __align__(16) f4 wl[8][1024];       // 131072 B
  __shared__ float gl[1024];
  __shared__ __align__(16) float hbuf[16][256];  // 16384 B  (total LDS ~152.5KB)
  const f4* wq4 = (const f4*)wq;                 // wq4[k4*1024 + row] = whh[row][4k4..]
  // resident register quads k4 = 0..17 (named vars: nothing for SROA to spill)
#define DECLR(i) f4 wr##i = wq4[(i) * 1024 + j];
  WREGS(DECLR)
#undef DECLR
  // LDS-resident quads k4 = 18..25
#pragma unroll
  for (int q = 0; q < 8; ++q) wl[q][j] = wq4[(18 + q) * 1024 + j];
  float c = 0.f;
  if (j < 256) { hs[j] = h_init[b * HID + j]; c = c_init[b * HID + j]; }
  __syncthreads();
  const f4* hs4 = (const f4*)hs;
  const f4* sp = wq4 + 26 * 1024 + j;            // streamed quads k4 = 26..63
  const float* gp = G + (size_t)b * 65536 + j;   // row n' = b*64+t
  float hlast = 0.f;
  for (int t = 0; t < T_; ++t) {
    float nd = ndb[t * B_ + b];
    f4 acc = {0.f, 0.f, 0.f, 0.f};
#define FMAR(i) { f4 h4 = hs4[i]; acc += h4 * wr##i; }
    WREGS(FMAR)
#undef FMAR
#pragma unroll
    for (int q = 0; q < 8; ++q) { f4 h4 = hs4[18 + q]; acc += h4 * wl[q][j]; }
#pragma unroll 4
    for (int q = 0; q < 38; ++q) { f4 h4 = hs4[26 + q]; acc += h4 * sp[(size_t)q * 1024]; }
    float g = gp[(size_t)t * 1024] + (acc.x + acc.y + acc.z + acc.w) * nd;
    gl[j] = g;
    __syncthreads();                             // gates ready
    if (j < 256) {
      float gi = gl[j], gf = gl[j + 256], gg = gl[j + 512], go = gl[j + 768];
      c = sigm(gf) * (c * nd) + sigm(gi) * tanh_(gg);
      float h = sigm(go) * tanh_(c);
      hs[j] = h;
      hbuf[t & 15][j] = h;
      hlast = h;
    }
    __syncthreads();                             // hs/hbuf updated
    if ((t & 15) == 15) {                        // flush 16-step tile, coalesced 64B/row
      int jr = j >> 2, qd = j & 3;               // jr 0..255, qd 0..3
      int t0 = t & ~15;
      float4 o4 = make_float4(hbuf[qd * 4 + 0][jr], hbuf[qd * 4 + 1][jr],
                              hbuf[qd * 4 + 2][jr], hbuf[qd * 4 + 3][jr]);
      *(float4*)&h_allT[(size_t)jr * 4096 + b * 64 + t0 + qd * 4] = o4;
    }
  }
  if (j < 256) { hT[b * HID + j] = hlast; cT[b * HID + j] = c; }
}

// ---------------- heads + argmax (merged): thread = output row n = t*64+b ----------
// h1aT columns are b*64+t -> col = (n&63)*64 + (n>>6).
__global__ __launch_bounds__(256)
void k_heads(const float* __restrict__ h1aT, const float* __restrict__ pwT,
             const float* __restrict__ pb, const float* __restrict__ bb,
             float* __restrict__ out) {
  int n = blockIdx.x * 256 + threadIdx.x;
  int col = ((n & 63) << 6) | (n >> 6);
  float acc[13];
#pragma unroll
  for (int o = 0; o < 12; ++o) acc[o] = pb[o];
  acc[12] = bb[0];
  for (int k = 0; k < 256; ++k) {
    float h = h1aT[(size_t)k * 4096 + col];
    const float* w = pwT + k * 16;               // uniform -> s_load
#pragma unroll
    for (int o = 0; o < 13; ++o) acc[o] += h * w[o];
  }
  float best = acc[0]; int bi = 0;
#pragma unroll
  for (int o = 1; o < 12; ++o)
    if (acc[o] > best) { best = acc[o]; bi = o; }   // strict > == first-max-wins
#pragma unroll
  for (int o = 0; o < 12; ++o) out[n * 12 + o] = acc[o];
  out[49152 + n] = acc[12];
  out[53248 + n] = (float)bi;
}

extern "C" void kernel_launch(void* const* d_in, const int* in_sizes, int n_in,
                              void* d_out, int out_size, void* d_ws, size_t ws_size,
                              hipStream_t stream) {
  const float* frame = (const float*)d_in[0];
  const unsigned char* done = (const unsigned char*)d_in[1];
  const float* h0 = (const float*)d_in[2];
  const float* c0 = (const float*)d_in[3];
  const float* cw1 = (const float*)d_in[4];  const float* cb1 = (const float*)d_in[5];
  const float* cw2 = (const float*)d_in[6];  const float* cb2 = (const float*)d_in[7];
  const float* cw3 = (const float*)d_in[8];  const float* cb3 = (const float*)d_in[9];
  const float* cw4 = (const float*)d_in[10]; const float* cb4 = (const float*)d_in[11];
  const float* wih0 = (const float*)d_in[12]; const float* whh0 = (const float*)d_in[13];
  const float* bih0 = (const float*)d_in[14]; const float* bhh0 = (const float*)d_in[15];
  const float* wih1 = (const float*)d_in[16]; const float* whh1 = (const float*)d_in[17];
  const float* bih1 = (const float*)d_in[18]; const float* bhh1 = (const float*)d_in[19];
  const float* pw = (const float*)d_in[20]; const float* pb = (const float*)d_in[21];
  const float* bw = (const float*)d_in[22]; const float* bb = (const float*)d_in[23];

  // workspace layout (~51 MB, all f32)
  float* featT = (float*)d_ws;                      //  1,179,648  [288][4096]
  float* G0    = featT + 1179648;                   //  4,194,304
  float* G1    = G0 + 4194304;                      //  4,194,304
  float* h0aT  = G1 + 4194304;                      //  1,048,576  [256][4096]
  float* h1aT  = h0aT + 1048576;                    //  1,048,576
  float* wih0T = h1aT + 1048576;                    //    294,912
  float* wih1T = wih0T + 294912;                    //    262,144
  float* wq0   = wih1T + 262144;                    //    262,144  whh0 quad layout
  float* wq1   = wq0 + 262144;                      //    262,144  whh1 quad layout
  float* wc2   = wq1 + 262144;                      //      9,216
  float* wc3   = wc2 + 9216;
  float* wc4   = wc3 + 9216;
  float* pwT   = wc4 + 9216;                        //      4,096
  float* ndb   = pwT + 4096;                        //      4,096

  float* out = (float*)d_out;
  float* o_hT = out + 57344;
  float* o_cT = out + 90112;

  k_prep<<<4348, 256, 0, stream>>>(wih0, wih1, whh0, whh1, cw2, cw3, cw4, pw, bw,
                                   wih0T, wih1T, wq0, wq1, wc2, wc3, wc4, pwT);
  k_donecvt<<<1, 1024, 0, stream>>>(done, ndb);
  k_convall<<<4096, 512, 0, stream>>>(frame, cw1, cb1, wc2, cb2, wc3, cb3, wc4, cb4,
                                      featT);
  k_gemm2<<<1024, 256, 0, stream>>>(featT, wih0T, bih0, bhh0, G0, 288);
  k_scan<<<64, 1024, 0, stream>>>(wq0, G0, h0, c0, ndb, h0aT, o_hT, o_cT);
  k_gemm2<<<1024, 256, 0, stream>>>(h0aT, wih1T, bih1, bhh1, G1, 256);
  k_scan<<<64, 1024, 0, stream>>>(wq1, G1, h0 + 16384, c0 + 16384, ndb, h1aT,
                                  o_hT + 16384, o_cT + 16384);
  k_heads<<<16, 256, 0, stream>>>(h1aT, pwT, pb, bb, out);
}

// Round 16
// 1660.878 us; speedup vs baseline: 2.0273x; 1.0215x over previous
//
#include <hip/hip_runtime.h>
#include <hip/hip_bf16.h>

// MarioDoomPolicyNet: conv stack (4x stride-2 + ELU) -> 2-layer LSTM scan -> heads.
// R11/R12: convall 577us (VGPR 56). R15: b*64+t layout + scan write tiling (1712.3).
// R13/R14: split-half conv DEAD. R16: persistent scan4 DEAD (compiler VGPR cap 128
//     -> spill; launch_bounds min-waves semantics unreliable per R13/R16 evidence).
// R21: scan residency 16->18 reg quads: 1696.5 us MEASURED BEST (-15.8 vs R15).
//     Verified dial: +2 reg quads = -5% streamed bytes = -15us total. Scans are
//     ~500us each (~1030 of 1696): L2-port-bound streaming W_hh from L2 every step.
// R22: residency 18->20 reg quads (+8 VGPR, est ~121 < 128 cap @ 4 waves/SIMD),
//     LDS quads k4 20..27, streamed 36 (k4 28..63). Ascending-k4 accumulation
//     unchanged -> bit-identical (absmax canary 0.0078125). Predict ~1675-1690.
// All f32 (precision requirement established R1/R2: argmax needs exact-ish logits).

#define T_ 64
#define B_ 64
#define NTB 4096
#define HID 256
#define G4 1024

typedef float f4 __attribute__((ext_vector_type(4)));

// XOR swizzle for LDS float4 slot j -> float column index (injective, 16B aligned)
#define XS(j) ((((j) << 2)) ^ ((((j) >> 3) & 7) << 2))

__device__ inline float sigm(float x) { return 1.f / (1.f + __expf(-x)); }
__device__ inline float tanh_(float x) { return 1.f - 2.f / (1.f + __expf(2.f * x)); }
__device__ inline float elu_(float x) { return x > 0.f ? x : __expf(x) - 1.f; }

// ---------------- prep: weight relayouts (all f32) ----------------
__global__ void k_prep(const float* __restrict__ wih0, const float* __restrict__ wih1,
                       const float* __restrict__ whh0, const float* __restrict__ whh1,
                       const float* __restrict__ cw2, const float* __restrict__ cw3,
                       const float* __restrict__ cw4, const float* __restrict__ pw,
                       const float* __restrict__ bw,
                       float* __restrict__ wih0T, float* __restrict__ wih1T,
                       float* __restrict__ wq0, float* __restrict__ wq1,
                       float* __restrict__ wc2, float* __restrict__ wc3,
                       float* __restrict__ wc4, float* __restrict__ pwT) {
  int idx = blockIdx.x * 256 + threadIdx.x;
  if (idx < 294912) {                       // wih0T[k*1024+j] = wih0[j*288+k]
    int k = idx >> 10, j = idx & 1023;
    wih0T[idx] = wih0[j * 288 + k];
  } else if (idx < 557056) {                // wih1T[k*1024+j] = wih1[j*256+k]
    int r = idx - 294912; int k = r >> 10, j = r & 1023;
    wih1T[r] = wih1[j * 256 + k];
  } else if (idx < 819200) {                // wq0[(k4*1024+row)*4+c] = whh0[row][4k4+c]
    int r = idx - 557056;
    int cc = r & 3, row = (r >> 2) & 1023, k4 = r >> 12;
    wq0[r] = whh0[row * 256 + k4 * 4 + cc];
  } else if (idx < 1081344) {
    int r = idx - 819200;
    int cc = r & 3, row = (r >> 2) & 1023, k4 = r >> 12;
    wq1[r] = whh1[row * 256 + k4 * 4 + cc];
  } else if (idx < 1108992) {               // conv weights -> [o][tap][i] f32
    int r = idx - 1081344;                  // 3 * 9216
    int which = r / 9216; int d = r - which * 9216;
    int i = d & 31, tap = (d >> 5) % 9, o = d / 288;
    int kh = tap / 3, kw = tap - kh * 3;
    const float* src = which == 0 ? cw2 : (which == 1 ? cw3 : cw4);
    float* dst = which == 0 ? wc2 : (which == 1 ? wc3 : wc4);
    dst[d] = src[((o * 32 + i) * 3 + kh) * 3 + kw];
  } else if (idx < 1113088) {               // pwT[k*16+o]: policy rows 0..11, baseline row 12
    int r = idx - 1108992; int k = r >> 4, o = r & 15;
    pwT[r] = o < 12 ? pw[o * 256 + k] : (o == 12 ? bw[k] : 0.f);
  }
}

// ---------------- done -> notdone float, robust to encoding (verified) ----------------
__global__ __launch_bounds__(1024)
void k_donecvt(const unsigned char* __restrict__ db, float* __restrict__ nd) {
  int tid = threadIdx.x;
  const unsigned* dw = (const unsigned*)db;
  unsigned w = dw[tid];
  int odd = ((w & 0xFFFFFF00u) != 0u && w != 0x3F800000u) ? 1 : 0;
  int any = __syncthreads_count(odd);
  bool u8 = (any > 0);
  for (int j = tid; j < 4096; j += 1024) {
    unsigned v = u8 ? (unsigned)db[j] : dw[j];
    nd[j] = v ? 0.f : 1.f;
  }
}

// ---------------- FUSED conv1..conv4: frame[n] -> featT[k][n'] (n' = b*64+t) ----------
// R11-exact structure. LDS 79872B -> 2 blk/CU. launch_bounds(512,8): VGPR 56 measured.
__global__ __launch_bounds__(512, 8)
void k_convall(const float* __restrict__ frame, const float* __restrict__ cw1,
               const float* __restrict__ cb1, const float* __restrict__ wc2,
               const float* __restrict__ cb2, const float* __restrict__ wc3,
               const float* __restrict__ cb3, const float* __restrict__ wc4,
               const float* __restrict__ cb4, float* __restrict__ featT) {
  __shared__ __align__(16) float a1t[8][1792];   // conv1 out: [oq][swizzled 441 pos x4]
  __shared__ __align__(16) float act2l[8][512];  // conv2 out: [oq][swizzled 121 pos x4]
  __shared__ __align__(16) float act3l[8][192];  // conv3 out: [oq][swizzled 36 pos x4]
  int n = blockIdx.x;
  int tid = threadIdx.x;
  const float4* fp = (const float4*)(frame + (size_t)n * 7056);
  int ncol = ((n & 63) << 6) | (n >> 6);         // b*64+t layout for downstream

  // ---- stage B: conv1 (frame direct from global, L1-cached 9x reuse) ----
  if (tid < 441) {
    int p = tid / 21, q = tid - (tid / 21) * 21;
    float px[9][4];
#pragma unroll
    for (int kh = 0; kh < 3; ++kh) {
#pragma unroll
      for (int kw = 0; kw < 3; ++kw) {
        int A = 2 * p - 1 + kh, Bc = 2 * q - 1 + kw;
        bool ok = ((unsigned)A < 42u) && ((unsigned)Bc < 42u);
        float4 v = ok ? fp[Bc * 42 + A] : make_float4(0.f, 0.f, 0.f, 0.f);
        px[kh * 3 + kw][0] = v.x; px[kh * 3 + kw][1] = v.y;
        px[kh * 3 + kw][2] = v.z; px[kh * 3 + kw][3] = v.w;
      }
    }
    int col = XS(tid);
#pragma unroll
    for (int oq = 0; oq < 8; ++oq) {
      float4 acc;
      float* ap = (float*)&acc;
#pragma unroll
      for (int j = 0; j < 4; ++j) {
        int o = oq * 4 + j;
        float a = cb1[o];
        const float* w = cw1 + o * 36;           // [c][kh][kw], scalar s_load
#pragma unroll
        for (int tap = 0; tap < 9; ++tap)
          a += px[tap][0] * w[tap] + px[tap][1] * w[9 + tap] +
               px[tap][2] * w[18 + tap] + px[tap][3] * w[27 + tap];
        ap[j] = elu_(a);
      }
      *(float4*)&a1t[oq][col] = acc;
    }
  }
  __syncthreads();

  // ---- stage C: conv2 (21x21x32 -> 11x11x32), thread = (pos, o-octet) ----
  {
    int s = tid & 127, oh = tid >> 7;            // oh 0..3, wave-uniform
    int ob = __builtin_amdgcn_readfirstlane(oh << 3);
    if (s < 121) {
      int p = s / 11, q = s - (s / 11) * 11;
      float acc[8];
#pragma unroll
      for (int oi = 0; oi < 8; ++oi) acc[oi] = cb2[ob + oi];
#pragma unroll
      for (int kh = 0; kh < 3; ++kh) {
        int A = 2 * p - 1 + kh;
        if ((unsigned)A >= 21u) continue;
#pragma unroll
        for (int kw = 0; kw < 3; ++kw) {
          int Bc = 2 * q - 1 + kw;
          if ((unsigned)Bc >= 21u) continue;
          int pos = A * 21 + Bc;
          int col = XS(pos);
          int tap = kh * 3 + kw;
#pragma unroll
          for (int i4 = 0; i4 < 8; ++i4) {
            float4 v = *(const float4*)&a1t[i4][col];
#pragma unroll
            for (int oi = 0; oi < 8; ++oi) {
              const float* w = wc2 + ((ob + oi) * 9 + tap) * 32 + i4 * 4;  // s_load
              acc[oi] += v.x * w[0] + v.y * w[1] + v.z * w[2] + v.w * w[3];
            }
          }
        }
      }
      int colw = XS(s);
#pragma unroll
      for (int half = 0; half < 2; ++half) {
        float4 o4 = make_float4(elu_(acc[half * 4 + 0]), elu_(acc[half * 4 + 1]),
                                elu_(acc[half * 4 + 2]), elu_(acc[half * 4 + 3]));
        *(float4*)&act2l[(ob >> 2) + half][colw] = o4;
      }
    }
  }
  __syncthreads();

  // ---- stage D: conv3 (11x11x32 -> 6x6x32), wave = o-quad, lanes = 36 pos ----
  {
    int wv = tid >> 6, lane = tid & 63;
    int oq = __builtin_amdgcn_readfirstlane(wv);
    if (lane < 36) {
      int p = lane / 6, q = lane - (lane / 6) * 6;
      float acc[4];
#pragma unroll
      for (int j = 0; j < 4; ++j) acc[j] = cb3[oq * 4 + j];
#pragma unroll
      for (int kh = 0; kh < 3; ++kh) {
        int A = 2 * p - 1 + kh;
        if ((unsigned)A >= 11u) continue;
#pragma unroll
        for (int kw = 0; kw < 3; ++kw) {
          int Bc = 2 * q - 1 + kw;
          if ((unsigned)Bc >= 11u) continue;
          int col = XS(A * 11 + Bc);
          int tap = kh * 3 + kw;
#pragma unroll
          for (int i4 = 0; i4 < 8; ++i4) {
            float4 v = *(const float4*)&act2l[i4][col];
#pragma unroll
            for (int j = 0; j < 4; ++j) {
              const float* w = wc3 + ((oq * 4 + j) * 9 + tap) * 32 + i4 * 4;  // s_load
              acc[j] += v.x * w[0] + v.y * w[1] + v.z * w[2] + v.w * w[3];
            }
          }
        }
      }
      float4 o4 = make_float4(elu_(acc[0]), elu_(acc[1]), elu_(acc[2]), elu_(acc[3]));
      *(float4*)&act3l[oq][XS(p * 6 + q)] = o4;
    }
  }
  __syncthreads();

  // ---- stage E: conv4 (6x6x32 -> 3x3x32), wave = o-quad, lanes = 9 pos; featT out ----
  {
    int wv = tid >> 6, lane = tid & 63;
    int oq = __builtin_amdgcn_readfirstlane(wv);
    if (lane < 9) {
      int p = lane / 3, q = lane - (lane / 3) * 3;
      float acc[4];
#pragma unroll
      for (int j = 0; j < 4; ++j) acc[j] = cb4[oq * 4 + j];
#pragma unroll
      for (int kh = 0; kh < 3; ++kh) {
        int A = 2 * p - 1 + kh;
        if ((unsigned)A >= 6u) continue;
#pragma unroll
        for (int kw = 0; kw < 3; ++kw) {
          int Bc = 2 * q - 1 + kw;
          if ((unsigned)Bc >= 6u) continue;
          int col = XS(A * 6 + Bc);
          int tap = kh * 3 + kw;
#pragma unroll
          for (int i4 = 0; i4 < 8; ++i4) {
            float4 v = *(const float4*)&act3l[i4][col];
#pragma unroll
            for (int j = 0; j < 4; ++j) {
              const float* w = wc4 + ((oq * 4 + j) * 9 + tap) * 32 + i4 * 4;  // s_load
              acc[j] += v.x * w[0] + v.y * w[1] + v.z * w[2] + v.w * w[3];
            }
          }
        }
      }
#pragma unroll
      for (int j = 0; j < 4; ++j)                // feat k = c*9 + p*3 + q
        featT[(size_t)((oq * 4 + j) * 9 + lane) * 4096 + ncol] = elu_(acc[j]);
    }
  }
}

// ---------------- GEMM on transposed input: out[n][j] = sum_k inT[k][n]*wT[k][j] + b ----
__global__ __launch_bounds__(256)
void k_gemm2(const float* __restrict__ inT, const float* __restrict__ wT,
             const float* __restrict__ b1, const float* __restrict__ b2,
             float* __restrict__ out, int K) {
  int nb = blockIdx.x >> 4, jb = blockIdx.x & 15;
  int lane = threadIdx.x & 63, wv = threadIdx.x >> 6;
  int n = nb * 64 + lane;
  int j0 = jb * 64 + __builtin_amdgcn_readfirstlane(wv << 4);
  float acc[16];
#pragma unroll
  for (int m = 0; m < 16; ++m) acc[m] = 0.f;
  const float* ip = inT + n;
#pragma unroll 4
  for (int k = 0; k < K; ++k) {
    float x = ip[(size_t)k * 4096];
    const float* w = wT + k * 1024 + j0;         // wave-uniform -> s_load x16
#pragma unroll
    for (int m = 0; m < 16; ++m) acc[m] += x * w[m];
  }
  float* op = out + (size_t)n * 1024 + j0;
#pragma unroll
  for (int h = 0; h < 4; ++h) {
    float4 o4 = make_float4(acc[h * 4 + 0] + b1[j0 + h * 4 + 0] + b2[j0 + h * 4 + 0],
                            acc[h * 4 + 1] + b1[j0 + h * 4 + 1] + b2[j0 + h * 4 + 1],
                            acc[h * 4 + 2] + b1[j0 + h * 4 + 2] + b2[j0 + h * 4 + 2],
                            acc[h * 4 + 3] + b1[j0 + h * 4 + 3] + b2[j0 + h * 4 + 3]);
    *(float4*)&op[h * 4] = o4;
  }
}

// ---------------- LSTM scan (one layer): 64 WGs, 1 batch elem each ----------------
// Hybrid-resident W_hh (R22 split): 20 reg quads (k4 0-19) + 8 LDS quads (20-27) +
// 36 streamed (28-63). Ascending k4 order -> bit-identical to R21/R15.
// G rows are n' = b*64+t (gp = G + b*65536 + j, step stride 1024). h buffered in
// LDS hbuf[16][256], flushed every 16 steps as full 64B lines (R15 write fix).
#define WREGS(X) X(0) X(1) X(2) X(3) X(4) X(5) X(6) X(7) \
                 X(8) X(9) X(10) X(11) X(12) X(13) X(14) X(15) \
                 X(16) X(17) X(18) X(19)

__global__ __launch_bounds__(1024, 4)
void k_scan(const float* __restrict__ wq, const float* __restrict__ G,
            const float* __restrict__ h_init, const float* __restrict__ c_init,
            const float* __restrict__ ndb, float* __restrict__ h_allT,
            float* __restrict__ hT, float* __restrict__ cT) {
  int b = blockIdx.x, j = threadIdx.x;
  __shared__ __align__(16) float hs[256];
  __shared__ __align__(16) f4 wl[8][1024];       // 131072 B
  __shared__ float gl[1024];
  __shared__ __align__(16) float hbuf[16][256];  // 16384 B  (total LDS ~152.5KB)
  const f4* wq4 = (const f4*)wq;                 // wq4[k4*1024 + row] = whh[row][4k4..]
  // resident register quads k4 = 0..19 (named vars: nothing for SROA to spill)
#define DECLR(i) f4 wr##i = wq4[(i) * 1024 + j];
  WREGS(DECLR)
#undef DECLR
  // LDS-resident quads k4 = 20..27
#pragma unroll
  for (int q = 0; q < 8; ++q) wl[q][j] = wq4[(20 + q) * 1024 + j];
  float c = 0.f;
  if (j < 256) { hs[j] = h_init[b * HID + j]; c = c_init[b * HID + j]; }
  __syncthreads();
  const f4* hs4 = (const f4*)hs;
  const f4* sp = wq4 + 28 * 1024 + j;            // streamed quads k4 = 28..63
  const float* gp = G + (size_t)b * 65536 + j;   // row n' = b*64+t
  float hlast = 0.f;
  for (int t = 0; t < T_; ++t) {
    float nd = ndb[t * B_ + b];
    f4 acc = {0.f, 0.f, 0.f, 0.f};
#define FMAR(i) { f4 h4 = hs4[i]; acc += h4 * wr##i; }
    WREGS(FMAR)
#undef FMAR
#pragma unroll
    for (int q = 0; q < 8; ++q) { f4 h4 = hs4[20 + q]; acc += h4 * wl[q][j]; }
#pragma unroll 4
    for (int q = 0; q < 36; ++q) { f4 h4 = hs4[28 + q]; acc += h4 * sp[(size_t)q * 1024]; }
    float g = gp[(size_t)t * 1024] + (acc.x + acc.y + acc.z + acc.w) * nd;
    gl[j] = g;
    __syncthreads();                             // gates ready
    if (j < 256) {
      float gi = gl[j], gf = gl[j + 256], gg = gl[j + 512], go = gl[j + 768];
      c = sigm(gf) * (c * nd) + sigm(gi) * tanh_(gg);
      float h = sigm(go) * tanh_(c);
      hs[j] = h;
      hbuf[t & 15][j] = h;
      hlast = h;
    }
    __syncthreads();                             // hs/hbuf updated
    if ((t & 15) == 15) {                        // flush 16-step tile, coalesced 64B/row
      int jr = j >> 2, qd = j & 3;               // jr 0..255, qd 0..3
      int t0 = t & ~15;
      float4 o4 = make_float4(hbuf[qd * 4 + 0][jr], hbuf[qd * 4 + 1][jr],
                              hbuf[qd * 4 + 2][jr], hbuf[qd * 4 + 3][jr]);
      *(float4*)&h_allT[(size_t)jr * 4096 + b * 64 + t0 + qd * 4] = o4;
    }
  }
  if (j < 256) { hT[b * HID + j] = hlast; cT[b * HID + j] = c; }
}

// ---------------- heads + argmax (merged): thread = output row n = t*64+b ----------
// h1aT columns are b*64+t -> col = (n&63)*64 + (n>>6).
__global__ __launch_bounds__(256)
void k_heads(const float* __restrict__ h1aT, const float* __restrict__ pwT,
             const float* __restrict__ pb, const float* __restrict__ bb,
             float* __restrict__ out) {
  int n = blockIdx.x * 256 + threadIdx.x;
  int col = ((n & 63) << 6) | (n >> 6);
  float acc[13];
#pragma unroll
  for (int o = 0; o < 12; ++o) acc[o] = pb[o];
  acc[12] = bb[0];
  for (int k = 0; k < 256; ++k) {
    float h = h1aT[(size_t)k * 4096 + col];
    const float* w = pwT + k * 16;               // uniform -> s_load
#pragma unroll
    for (int o = 0; o < 13; ++o) acc[o] += h * w[o];
  }
  float best = acc[0]; int bi = 0;
#pragma unroll
  for (int o = 1; o < 12; ++o)
    if (acc[o] > best) { best = acc[o]; bi = o; }   // strict > == first-max-wins
#pragma unroll
  for (int o = 0; o < 12; ++o) out[n * 12 + o] = acc[o];
  out[49152 + n] = acc[12];
  out[53248 + n] = (float)bi;
}

extern "C" void kernel_launch(void* const* d_in, const int* in_sizes, int n_in,
                              void* d_out, int out_size, void* d_ws, size_t ws_size,
                              hipStream_t stream) {
  const float* frame = (const float*)d_in[0];
  const unsigned char* done = (const unsigned char*)d_in[1];
  const float* h0 = (const float*)d_in[2];
  const float* c0 = (const float*)d_in[3];
  const float* cw1 = (const float*)d_in[4];  const float* cb1 = (const float*)d_in[5];
  const float* cw2 = (const float*)d_in[6];  const float* cb2 = (const float*)d_in[7];
  const float* cw3 = (const float*)d_in[8];  const float* cb3 = (const float*)d_in[9];
  const float* cw4 = (const float*)d_in[10]; const float* cb4 = (const float*)d_in[11];
  const float* wih0 = (const float*)d_in[12]; const float* whh0 = (const float*)d_in[13];
  const float* bih0 = (const float*)d_in[14]; const float* bhh0 = (const float*)d_in[15];
  const float* wih1 = (const float*)d_in[16]; const float* whh1 = (const float*)d_in[17];
  const float* bih1 = (const float*)d_in[18]; const float* bhh1 = (const float*)d_in[19];
  const float* pw = (const float*)d_in[20]; const float* pb = (const float*)d_in[21];
  const float* bw = (const float*)d_in[22]; const float* bb = (const float*)d_in[23];

  // workspace layout (~51 MB, all f32)
  float* featT = (float*)d_ws;                      //  1,179,648  [288][4096]
  float* G0    = featT + 1179648;                   //  4,194,304
  float* G1    = G0 + 4194304;                      //  4,194,304
  float* h0aT  = G1 + 4194304;                      //  1,048,576  [256][4096]
  float* h1aT  = h0aT + 1048576;                    //  1,048,576
  float* wih0T = h1aT + 1048576;                    //    294,912
  float* wih1T = wih0T + 294912;                    //    262,144
  float* wq0   = wih1T + 262144;                    //    262,144  whh0 quad layout
  float* wq1   = wq0 + 262144;                      //    262,144  whh1 quad layout
  float* wc2   = wq1 + 262144;                      //      9,216
  float* wc3   = wc2 + 9216;
  float* wc4   = wc3 + 9216;
  float* pwT   = wc4 + 9216;                        //      4,096
  float* ndb   = pwT + 4096;                        //      4,096

  float* out = (float*)d_out;
  float* o_hT = out + 57344;
  float* o_cT = out + 90112;

  k_prep<<<4348, 256, 0, stream>>>(wih0, wih1, whh0, whh1, cw2, cw3, cw4, pw, bw,
                                   wih0T, wih1T, wq0, wq1, wc2, wc3, wc4, pwT);
  k_donecvt<<<1, 1024, 0, stream>>>(done, ndb);
  k_convall<<<4096, 512, 0, stream>>>(frame, cw1, cb1, wc2, cb2, wc3, cb3, wc4, cb4,
                                      featT);
  k_gemm2<<<1024, 256, 0, stream>>>(featT, wih0T, bih0, bhh0, G0, 288);
  k_scan<<<64, 1024, 0, stream>>>(wq0, G0, h0, c0, ndb, h0aT, o_hT, o_cT);
  k_gemm2<<<1024, 256, 0, stream>>>(h0aT, wih1T, bih1, bhh1, G1, 256);
  k_scan<<<64, 1024, 0, stream>>>(wq1, G1, h0 + 16384, c0 + 16384, ndb, h1aT,
                                  o_hT + 16384, o_cT + 16384);
  k_heads<<<16, 256, 0, stream>>>(h1aT, pwT, pb, bb, out);
}